// Round 1
// baseline (327.089 us; speedup 1.0000x reference)
//
#include <hip/hip_runtime.h>
#include <hip/hip_bf16.h>
#include <stdint.h>

#define VOXEL_SIZE_F 0.4f
#define GAMMA_F 1.1f

// dx*dx + dy*dy with contraction blocked (bit-exact vs numpy: mul,add both RN)
__device__ __forceinline__ float sq2_rn(float dx, float dy) {
    float a = __fmul_rn(dx, dx);
    float b = __fmul_rn(dy, dy);
    return __fadd_rn(a, b);
}

// ---------------- Kernel A: voxel-level radius search ----------------
// voxel_mask[v] = any_r ( |query_coords[r] - coords[v]| < radii_vox[r] )
__global__ void k_voxel_mask(const float* __restrict__ boxes,
                             const float* __restrict__ pc_start,
                             const int* __restrict__ coords,
                             int V, int R,
                             unsigned char* __restrict__ vmask,
                             float* __restrict__ out_vox) {
    __shared__ float qx[256], qy[256], rv[256];
    int t = threadIdx.x;
    int v = blockIdx.x * blockDim.x + t;
    float psx = pc_start[0], psy = pc_start[1];
    float cxf = 0.f, cyf = 0.f;
    if (v < V) { cxf = (float)coords[2 * v]; cyf = (float)coords[2 * v + 1]; }
    int m = 0;
    for (int rb = 0; rb < R; rb += 256) {
        int rt = rb + t;
        if (rt < R) {
            float bx = boxes[rt * 7 + 0], by = boxes[rt * 7 + 1];
            float hx = boxes[rt * 7 + 3] * 0.5f;
            float hy = boxes[rt * 7 + 4] * 0.5f;
            float nrm = sqrtf(sq2_rn(hx, hy));
            qx[t] = (bx - psx) / VOXEL_SIZE_F;
            qy[t] = (by - psy) / VOXEL_SIZE_F;
            rv[t] = (nrm * GAMMA_F) / VOXEL_SIZE_F;
        }
        __syncthreads();
        int tile = (R - rb) < 256 ? (R - rb) : 256;
        if (v < V && !m) {
            for (int j = 0; j < tile; j++) {
                float dx = qx[j] - cxf;
                float dy = qy[j] - cyf;
                float d = sqrtf(sq2_rn(dx, dy));
                if (d < rv[j]) { m = 1; break; }   // strict < (reference)
            }
        }
        __syncthreads();
    }
    if (v < V) {
        vmask[v] = (unsigned char)m;
        out_vox[v] = m ? 1.0f : 0.0f;
    }
}

// ---------------- Kernel B: order-preserving compaction of active voxels ----
// act[i] = vid | (clamped_num_points << 16), ascending vid order.
__global__ void k_scan(const unsigned char* __restrict__ vmask,
                       const int* __restrict__ num_points,
                       int V, int K,
                       int* __restrict__ act, int* __restrict__ act_count) {
    __shared__ int wsum[16];
    __shared__ int sbase;
    int t = threadIdx.x;
    int lane = t & 63, wid = t >> 6;
    int NW = blockDim.x >> 6;
    if (t == 0) sbase = 0;
    __syncthreads();
    int nchunk = (V + blockDim.x - 1) / blockDim.x;
    unsigned long long ltmask = (1ull << lane) - 1ull;
    for (int c = 0; c < nchunk; c++) {
        int v = c * blockDim.x + t;
        int m = (v < V) ? (int)vmask[v] : 0;
        unsigned long long bal = __ballot(m != 0);
        if (lane == 0) wsum[wid] = __popcll(bal);
        __syncthreads();
        int wbase = sbase;
        for (int w = 0; w < wid; w++) wbase += wsum[w];
        int total = 0;
        for (int w = 0; w < NW; w++) total += wsum[w];
        if (m) {
            int rank = __popcll(bal & ltmask);
            int np_ = num_points[v];
            if (np_ < 0) np_ = 0;
            if (np_ > K) np_ = K;
            act[wbase + rank] = v | (np_ << 16);
        }
        __syncthreads();
        if (t == 0) sbase += total;
        __syncthreads();
    }
    if (t == 0) *act_count = sbase;
}

// ---------------- Kernel D: per-ROI ordered capped selection ----------------
// One wave (64 threads) per ROI. Each chunk covers 4 active voxels x 16 pts.
// Ballot+prefix-popcount gives the in-order append position (== stable top_k
// of a 0/1 mask). Unroll x8 to batch the act->xy dependent-load chain.
__global__ void k_select(const float* __restrict__ voxels,
                         const float* __restrict__ boxes,
                         const int* __restrict__ act,
                         const int* __restrict__ act_count,
                         int K, int F, int S,
                         float* __restrict__ out_kp,
                         float* __restrict__ out_mask) {
    __shared__ int sel[1024];
    int r = blockIdx.x;
    int lane = threadIdx.x;          // block = 64 = 1 wave
    float bx = boxes[r * 7 + 0], by = boxes[r * 7 + 1];
    float hx = boxes[r * 7 + 3] * 0.5f, hy = boxes[r * 7 + 4] * 0.5f;
    float rad = sqrtf(sq2_rn(hx, hy)) * GAMMA_F;   // point-level radius (meters)
    int A = *act_count;
    int k = lane & 15;
    int qq = lane >> 4;
    int count = 0;
    int nch = (A + 3) >> 2;          // chunks of 4 voxels
    unsigned long long ltmask = (1ull << lane) - 1ull;

    for (int c0 = 0; c0 < nch && count < S; c0 += 8) {
        int a[8];
        float px[8], py[8];
        #pragma unroll
        for (int u = 0; u < 8; u++) {
            int slot = (c0 + u) * 4 + qq;
            a[u] = (slot < A) ? act[slot] : 0;   // a=0 -> vid 0, cnt 0 -> pred false
        }
        #pragma unroll
        for (int u = 0; u < 8; u++) {
            int vid = a[u] & 0xFFFF;
            int n = vid * K + k;                 // always in-bounds (vid<V, k<K)
            px[u] = voxels[n * F + 0];
            py[u] = voxels[n * F + 1];
        }
        #pragma unroll
        for (int u = 0; u < 8; u++) {
            int slot = (c0 + u) * 4 + qq;
            int cnt = a[u] >> 16;
            int pred = 0;
            if (slot < A && k < cnt) {
                float dx = px[u] - bx, dy = py[u] - by;
                pred = (sqrtf(sq2_rn(dx, dy)) <= rad) ? 1 : 0;  // non-strict <=
            }
            unsigned long long bal = __ballot(pred);
            int pos = count + __popcll(bal & ltmask);
            if (pred && pos < S) {
                int vid = a[u] & 0xFFFF;
                sel[pos] = vid * K + k;
            }
            count += __popcll(bal);
        }
    }

    int scount = count < S ? count : S;
    __syncthreads();   // order LDS writes before cross-lane reads

    for (int s = lane; s < S; s += 64) {
        float mv = (s < scount) ? 1.0f : 0.0f;
        out_mask[(size_t)r * S + s] = mv;
        float f[8];
        #pragma unroll
        for (int j = 0; j < 8; j++) f[j] = 0.f;
        if (s < scount) {
            int n = sel[s];
            for (int j = 0; j < F; j++) f[j] = voxels[(size_t)n * F + j];
        }
        float* o = out_kp + ((size_t)r * S + s) * F;
        for (int j = 0; j < F; j++) o[j] = f[j];
    }
}

extern "C" void kernel_launch(void* const* d_in, const int* in_sizes, int n_in,
                              void* d_out, int out_size, void* d_ws, size_t ws_size,
                              hipStream_t stream) {
    const float* voxels   = (const float*)d_in[0];
    const float* boxes    = (const float*)d_in[1];
    const float* pc_start = (const float*)d_in[2];
    const int*   coords   = (const int*)d_in[3];
    const int*   num_pts  = (const int*)d_in[4];
    // d_in[5] = num_sample (on device) — S derived from out_size instead.

    int V = in_sizes[4];                 // 20000
    int R = in_sizes[1] / 7;             // 256
    int K = 16;                          // per reference setup
    int F = (in_sizes[0] / V) / K;       // 5
    int S = (out_size - V) / (R * (F + 1));  // 128

    float* out_kp  = (float*)d_out;                       // [R,S,F]
    float* out_msk = out_kp + (size_t)R * S * F;          // [R,S]
    float* out_vox = out_msk + (size_t)R * S;             // [V]

    unsigned char* vmask = (unsigned char*)d_ws;          // V bytes
    size_t off = ((size_t)V + 255) & ~(size_t)255;
    int* act_count = (int*)((char*)d_ws + off);           // 1 int (+pad)
    int* act = act_count + 64;                            // V ints max

    dim3 bA(256), gA((V + 255) / 256);
    k_voxel_mask<<<gA, bA, 0, stream>>>(boxes, pc_start, coords, V, R, vmask, out_vox);
    k_scan<<<1, 1024, 0, stream>>>(vmask, num_pts, V, K, act, act_count);
    k_select<<<R, 64, 0, stream>>>(voxels, boxes, act, act_count, K, F, S, out_kp, out_msk);
}

// Round 2
// 154.881 us; speedup vs baseline: 2.1119x; 2.1119x over previous
//
#include <hip/hip_runtime.h>
#include <hip/hip_bf16.h>
#include <stdint.h>

#define VOXEL_SIZE_F 0.4f
#define GAMMA_F 1.1f

// dx*dx + dy*dy with contraction blocked (bit-exact vs numpy: mul,add both RN)
__device__ __forceinline__ float sq2_rn(float dx, float dy) {
    float a = __fmul_rn(dx, dx);
    float b = __fmul_rn(dy, dy);
    return __fadd_rn(a, b);
}

__device__ __forceinline__ int wave_incl_scan(int v, int lane) {
    #pragma unroll
    for (int d = 1; d < 64; d <<= 1) {
        int t = __shfl_up(v, d, 64);
        if (lane >= d) v += t;
    }
    return v;
}

// ---------------- Kernel A: voxel-level radius search + per-block counts ----
// block = 64 threads (1 wave), one voxel per thread, branchless 256-box loop.
__global__ void k_voxel_mask(const float* __restrict__ boxes,
                             const float* __restrict__ pc_start,
                             const int* __restrict__ coords,
                             int V, int R,
                             unsigned char* __restrict__ vmask,
                             float* __restrict__ out_vox,
                             int* __restrict__ bc) {
    __shared__ float qx[256], qy[256], rv[256];
    int lane = threadIdx.x;
    float psx = pc_start[0], psy = pc_start[1];
    int v = blockIdx.x * 64 + lane;
    float cxf = 0.f, cyf = 0.f;
    if (v < V) { cxf = (float)coords[2 * v]; cyf = (float)coords[2 * v + 1]; }
    int m = 0;
    for (int rb = 0; rb < R; rb += 256) {
        int tile = (R - rb) < 256 ? (R - rb) : 256;
        for (int j = lane; j < tile; j += 64) {
            int rt = rb + j;
            float bx = boxes[rt * 7 + 0], by = boxes[rt * 7 + 1];
            float hx = boxes[rt * 7 + 3] * 0.5f;
            float hy = boxes[rt * 7 + 4] * 0.5f;
            float nrm = sqrtf(sq2_rn(hx, hy));
            qx[j] = (bx - psx) / VOXEL_SIZE_F;
            qy[j] = (by - psy) / VOXEL_SIZE_F;
            rv[j] = (nrm * GAMMA_F) / VOXEL_SIZE_F;
        }
        __syncthreads();
        #pragma unroll 4
        for (int j = 0; j < tile; j++) {
            float dx = qx[j] - cxf;
            float dy = qy[j] - cyf;
            m |= (sqrtf(sq2_rn(dx, dy)) < rv[j]) ? 1 : 0;   // strict <
        }
        __syncthreads();
    }
    int am = (v < V) ? m : 0;
    unsigned long long bal = __ballot(am != 0);
    if (lane == 0) bc[blockIdx.x] = __popcll(bal);
    if (v < V) {
        vmask[v] = (unsigned char)am;
        out_vox[v] = am ? 1.0f : 0.0f;
    }
}

// ---------------- Kernel B: parallel order-preserving compaction ------------
// block = 64 (1 wave), block b handles voxels [b*64, b*64+64).
// Each block prefix-sums bc[] itself (nb<=~320 -> 5 wave-scan rounds).
// Emits act[] (vid | np<<16) and compacted point xy with NaN for invalid pts.
__global__ void k_compact(const unsigned char* __restrict__ vmask,
                          const int* __restrict__ num_points,
                          const float* __restrict__ voxels,
                          int V, int K, int F, int nb,
                          const int* __restrict__ bc,
                          int* __restrict__ act, int* __restrict__ act_count,
                          float* __restrict__ apx, float* __restrict__ apy) {
    __shared__ int sbase;
    __shared__ int lvid[64], lnp[64];
    int b = blockIdx.x;
    int lane = threadIdx.x;
    if (lane == 0) sbase = 0;
    __syncthreads();
    int run = 0;
    for (int i0 = 0; i0 < nb; i0 += 64) {
        int i = i0 + lane;
        int val = (i < nb) ? bc[i] : 0;
        int incl = wave_incl_scan(val, lane);
        if (i == b) sbase = run + incl - val;   // exclusive prefix at b
        run += __shfl(incl, 63, 64);
    }
    if (b == 0 && lane == 0) *act_count = run;
    __syncthreads();
    int base = sbase;

    int v = b * 64 + lane;
    int m = (v < V) ? (int)vmask[v] : 0;
    unsigned long long bal = __ballot(m != 0);
    unsigned long long ltmask = (1ull << lane) - 1ull;
    int rank = __popcll(bal & ltmask);
    int cnt = __popcll(bal);
    if (m) {
        int np_ = num_points[v];
        if (np_ < 0) np_ = 0;
        if (np_ > K) np_ = K;
        act[base + rank] = v | (np_ << 16);
        lvid[rank] = v;
        lnp[rank] = np_;
    }
    __syncthreads();
    const float NANF = __int_as_float(0x7FC00000);
    int npts = cnt * 16;
    for (int j = lane; j < npts; j += 64) {
        int ri = j >> 4, k = j & 15;
        int vid = lvid[ri], np_ = lnp[ri];
        float x = NANF, y = NANF;
        if (k < np_) {
            size_t n = (size_t)(vid * K + k) * F;
            x = voxels[n + 0];
            y = voxels[n + 1];
        }
        apx[(size_t)base * 16 + j] = x;
        apy[(size_t)base * 16 + j] = y;
    }
}

// ---------------- Kernel C: per-(ROI, chunk) match counts -------------------
// grid-stride over R*nch work items; chunk = 256 points; block = 256.
__global__ void k_count(const float* __restrict__ apx, const float* __restrict__ apy,
                        const float* __restrict__ boxes,
                        const int* __restrict__ act_count,
                        int R, int* __restrict__ counts) {
    int A16 = (*act_count) << 4;
    int nch = (A16 + 255) >> 8;
    int total = R * nch;
    int tid = threadIdx.x, lane = tid & 63, wid = tid >> 6;
    __shared__ int wsum[4];
    for (int w = blockIdx.x; w < total; w += gridDim.x) {
        int r = w / nch, c = w - r * nch;
        float bx = boxes[r * 7 + 0], by = boxes[r * 7 + 1];
        float hx = boxes[r * 7 + 3] * 0.5f, hy = boxes[r * 7 + 4] * 0.5f;
        float rad = sqrtf(sq2_rn(hx, hy)) * GAMMA_F;
        int p = (c << 8) + tid;
        int pred = 0;
        if (p < A16) {
            float dx = apx[p] - bx, dy = apy[p] - by;
            pred = (sqrtf(sq2_rn(dx, dy)) <= rad) ? 1 : 0;  // NaN -> false
        }
        unsigned long long bal = __ballot(pred != 0);
        if (lane == 0) wsum[wid] = __popcll(bal);
        __syncthreads();
        if (tid == 0) counts[w] = wsum[0] + wsum[1] + wsum[2] + wsum[3];
        __syncthreads();
    }
}

// ---------------- Kernel D: per-ROI prefix over chunk counts ----------------
__global__ void k_scan_counts(const int* __restrict__ counts,
                              const int* __restrict__ act_count,
                              int R, int S,
                              int* __restrict__ bases, int* __restrict__ scount) {
    int A16 = (*act_count) << 4;
    int nch = (A16 + 255) >> 8;
    int r = blockIdx.x;
    int lane = threadIdx.x;
    int run = 0;
    for (int i0 = 0; i0 < nch; i0 += 64) {
        int i = i0 + lane;
        int val = (i < nch) ? counts[r * nch + i] : 0;
        int incl = wave_incl_scan(val, lane);
        if (i < nch) bases[r * nch + i] = run + incl - val;  // exclusive
        run += __shfl(incl, 63, 64);
    }
    if (lane == 0) scount[r] = run < S ? run : S;
}

// ---------------- Kernel E: ordered emit (recompute + ballot rank) ----------
__global__ void k_emit(const float* __restrict__ apx, const float* __restrict__ apy,
                       const float* __restrict__ voxels,
                       const float* __restrict__ boxes,
                       const int* __restrict__ act,
                       const int* __restrict__ act_count,
                       const int* __restrict__ bases,
                       int R, int K, int F, int S,
                       float* __restrict__ out_kp) {
    int A16 = (*act_count) << 4;
    int nch = (A16 + 255) >> 8;
    int total = R * nch;
    int tid = threadIdx.x, lane = tid & 63, wid = tid >> 6;
    unsigned long long ltmask = (1ull << lane) - 1ull;
    __shared__ int wsum[4];
    for (int w = blockIdx.x; w < total; w += gridDim.x) {
        int cbase = bases[w];
        if (cbase >= S) continue;           // uniform per block: safe
        int r = w / nch, c = w - r * nch;
        float bx = boxes[r * 7 + 0], by = boxes[r * 7 + 1];
        float hx = boxes[r * 7 + 3] * 0.5f, hy = boxes[r * 7 + 4] * 0.5f;
        float rad = sqrtf(sq2_rn(hx, hy)) * GAMMA_F;
        int p = (c << 8) + tid;
        int pred = 0;
        if (p < A16) {
            float dx = apx[p] - bx, dy = apy[p] - by;
            pred = (sqrtf(sq2_rn(dx, dy)) <= rad) ? 1 : 0;
        }
        unsigned long long bal = __ballot(pred != 0);
        if (lane == 0) wsum[wid] = __popcll(bal);
        __syncthreads();
        int wbase = cbase;
        for (int i = 0; i < wid; i++) wbase += wsum[i];
        int pos = wbase + __popcll(bal & ltmask);
        if (pred && pos < S) {
            int slot = p >> 4, k = p & 15;
            int vid = act[slot] & 0xFFFF;
            const float* src = voxels + (size_t)(vid * K + k) * F;
            float* dst = out_kp + ((size_t)r * S + pos) * F;
            #pragma unroll
            for (int j = 0; j < 5; j++) dst[j] = src[j];
        }
        __syncthreads();
    }
}

// ---------------- Kernel F: mask + zero tail of key_points ------------------
__global__ void k_fill(const int* __restrict__ scount,
                       int R, int S, int F,
                       float* __restrict__ out_kp, float* __restrict__ out_mask) {
    int idx = blockIdx.x * blockDim.x + threadIdx.x;
    if (idx >= R * S) return;
    int r = idx / S, s = idx - r * S;
    int sc = scount[r];
    out_mask[idx] = (s < sc) ? 1.0f : 0.0f;
    if (s >= sc) {
        float* dst = out_kp + (size_t)idx * F;
        #pragma unroll
        for (int j = 0; j < 5; j++) dst[j] = 0.0f;
    }
}

extern "C" void kernel_launch(void* const* d_in, const int* in_sizes, int n_in,
                              void* d_out, int out_size, void* d_ws, size_t ws_size,
                              hipStream_t stream) {
    const float* voxels   = (const float*)d_in[0];
    const float* boxes    = (const float*)d_in[1];
    const float* pc_start = (const float*)d_in[2];
    const int*   coords   = (const int*)d_in[3];
    const int*   num_pts  = (const int*)d_in[4];

    int V = in_sizes[4];                     // 20000
    int R = in_sizes[1] / 7;                 // 256
    int K = 16;
    int F = (in_sizes[0] / V) / K;           // 5
    int S = (out_size - V) / (R * (F + 1));  // 128
    int nb = (V + 63) / 64;                  // 313
    int nchmax = (V * K + 255) / 256;        // 1250

    float* out_kp  = (float*)d_out;                 // [R,S,F]
    float* out_msk = out_kp + (size_t)R * S * F;    // [R,S]
    float* out_vox = out_msk + (size_t)R * S;       // [V]

    // workspace carve (256B aligned)
    char* w = (char*)d_ws;
    auto carve = [&](size_t bytes) {
        void* p = (void*)w;
        w += (bytes + 255) & ~(size_t)255;
        return p;
    };
    unsigned char* vmask = (unsigned char*)carve((size_t)V);
    int*   bc        = (int*)carve((size_t)nb * 4);
    int*   act_count = (int*)carve(4);
    int*   act       = (int*)carve((size_t)V * 4);
    float* apx       = (float*)carve((size_t)V * K * 4);
    float* apy       = (float*)carve((size_t)V * K * 4);
    int*   counts    = (int*)carve((size_t)R * nchmax * 4);
    int*   bases     = (int*)carve((size_t)R * nchmax * 4);
    int*   scount    = (int*)carve((size_t)R * 4);

    k_voxel_mask<<<nb, 64, 0, stream>>>(boxes, pc_start, coords, V, R,
                                        vmask, out_vox, bc);
    k_compact<<<nb, 64, 0, stream>>>(vmask, num_pts, voxels, V, K, F, nb,
                                     bc, act, act_count, apx, apy);
    k_count<<<2048, 256, 0, stream>>>(apx, apy, boxes, act_count, R, counts);
    k_scan_counts<<<R, 64, 0, stream>>>(counts, act_count, R, S, bases, scount);
    k_emit<<<2048, 256, 0, stream>>>(apx, apy, voxels, boxes, act, act_count,
                                     bases, R, K, F, S, out_kp);
    k_fill<<<(R * S + 255) / 256, 256, 0, stream>>>(scount, R, S, F,
                                                    out_kp, out_msk);
}

// Round 4
// 111.455 us; speedup vs baseline: 2.9347x; 1.3896x over previous
//
#include <hip/hip_runtime.h>
#include <hip/hip_bf16.h>
#include <stdint.h>

#define VOXEL_SIZE_F 0.4f
#define GAMMA_F 1.1f
#define SLACK_F 0.0625f   // covers all f32 rounding in the triangle-inequality filter

// dx*dx + dy*dy with contraction blocked (bit-exact vs numpy: mul,add both RN)
__device__ __forceinline__ float sq2_rn(float dx, float dy) {
    return __fadd_rn(__fmul_rn(dx, dx), __fmul_rn(dy, dy));
}

__device__ __forceinline__ int wave_incl_scan(int v, int lane) {
    #pragma unroll
    for (int d = 1; d < 64; d <<= 1) {
        int t = __shfl_up(v, d, 64);
        if (lane >= d) v += t;
    }
    return v;
}

// ---- K1: voxel-level radius search + per-voxel max point offset + counts ---
// block = 64 (1 wave), one voxel per thread.
__global__ void k1_mask(const float* __restrict__ boxes,
                        const float* __restrict__ pc_start,
                        const int* __restrict__ coords,
                        const int* __restrict__ num_points,
                        const float* __restrict__ voxels,
                        int V, int R, int K, int F,
                        unsigned char* __restrict__ vstat,
                        float* __restrict__ vmaxoff,
                        float* __restrict__ out_vox,
                        int* __restrict__ bc) {
    __shared__ float qx[256], qy[256], rv[256];
    int lane = threadIdx.x;
    int v = blockIdx.x * 64 + lane;
    float psx = pc_start[0], psy = pc_start[1];
    float cxf = 0.f, cyf = 0.f;
    int np = 0;
    if (v < V) {
        cxf = (float)coords[2 * v];
        cyf = (float)coords[2 * v + 1];
        np = num_points[v];
        np = np < 0 ? 0 : (np > K ? K : np);
    }
    int m = 0;
    for (int rb = 0; rb < R; rb += 256) {
        int tile = (R - rb) < 256 ? (R - rb) : 256;
        for (int j = lane; j < tile; j += 64) {
            const float* bp = boxes + (size_t)(rb + j) * 7;
            float hx = bp[3] * 0.5f, hy = bp[4] * 0.5f;
            qx[j] = (bp[0] - psx) / VOXEL_SIZE_F;
            qy[j] = (bp[1] - psy) / VOXEL_SIZE_F;
            rv[j] = (sqrtf(sq2_rn(hx, hy)) * GAMMA_F) / VOXEL_SIZE_F;
        }
        __syncthreads();
        #pragma unroll 4
        for (int j = 0; j < tile; j++) {
            float dx = qx[j] - cxf, dy = qy[j] - cyf;
            m |= (sqrtf(sq2_rn(dx, dy)) < rv[j]) ? 1 : 0;   // strict < (reference)
        }
        __syncthreads();
    }
    int am = (v < V) ? m : 0;
    unsigned long long bal = __ballot(am != 0);
    if (lane == 0) bc[blockIdx.x] = __popcll(bal);
    float mo = -1e30f;   // np==0 or unmasked -> never a candidate
    if (am && np > 0) {
        float cxm = cxf * VOXEL_SIZE_F + psx;
        float cym = cyf * VOXEL_SIZE_F + psy;
        const float* pv = voxels + (size_t)v * K * F;
        for (int k = 0; k < np; k++) {
            float px = pv[k * F + 0], py = pv[k * F + 1];
            float d = sqrtf(sq2_rn(px - cxm, py - cym));
            mo = fmaxf(mo, d);
        }
    }
    if (v < V) {
        vstat[v] = am ? (unsigned char)(np + 1) : 0;
        vmaxoff[v] = mo;
        out_vox[v] = am ? 1.0f : 0.0f;
    }
}

// ---- K2: parallel order-preserving compaction into one float4 stream -------
// actq[i] = {center_x_m, center_y_m, maxoff, bits(vid | np<<16)}, ascending vid.
__global__ void k2_compact(const unsigned char* __restrict__ vstat,
                           const float* __restrict__ vmaxoff,
                           const int* __restrict__ coords,
                           const float* __restrict__ pc_start,
                           int V, int nb,
                           const int* __restrict__ bc,
                           float4* __restrict__ actq,
                           int* __restrict__ act_count) {
    __shared__ int sbase;
    int b = blockIdx.x;
    int lane = threadIdx.x;
    if (lane == 0) sbase = 0;
    __syncthreads();
    int run = 0;
    for (int i0 = 0; i0 < nb; i0 += 64) {
        int i = i0 + lane;
        int val = (i < nb) ? bc[i] : 0;
        int incl = wave_incl_scan(val, lane);
        if (i == b) sbase = run + incl - val;   // exclusive prefix at block b
        run += __shfl(incl, 63, 64);
    }
    if (b == 0 && lane == 0) *act_count = run;
    __syncthreads();
    int base = sbase;

    int v = b * 64 + lane;
    int stat = (v < V) ? (int)vstat[v] : 0;
    int m = stat > 0;
    unsigned long long bal = __ballot(m != 0);
    unsigned long long ltmask = (1ull << lane) - 1ull;
    int rank = __popcll(bal & ltmask);
    if (m) {
        float psx = pc_start[0], psy = pc_start[1];
        float cxm = (float)coords[2 * v] * VOXEL_SIZE_F + psx;
        float cym = (float)coords[2 * v + 1] * VOXEL_SIZE_F + psy;
        float4 q;
        q.x = cxm;
        q.y = cym;
        q.z = vmaxoff[v];
        q.w = __int_as_float(v | ((stat - 1) << 16));
        actq[base + rank] = q;
    }
}

// ---- K3: one block per ROI — candidate filter + exact ordered selection ----
// 256 threads (4 waves). Stream act in chunks of 256; triangle-inequality
// candidate filter; ordered block-compact survivors to LDS; exact point test
// 16 voxels x 16 pts per sub-round with block-wide ordered ballot rank.
__global__ void k3_roi(const float* __restrict__ voxels,
                       const float* __restrict__ boxes,
                       const float4* __restrict__ actq,
                       const int* __restrict__ act_count,
                       int K, int F, int S,
                       float* __restrict__ out_kp,
                       float* __restrict__ out_mask) {
    __shared__ float4 cq[256];
    __shared__ int wsum[4];
    int r = blockIdx.x;
    int tid = threadIdx.x, lane = tid & 63, wid = tid >> 6;
    unsigned long long ltmask = (1ull << lane) - 1ull;

    const float* bp = boxes + (size_t)r * 7;
    float bx = bp[0], by = bp[1];
    float hx = bp[3] * 0.5f, hy = bp[4] * 0.5f;
    float rad = sqrtf(sq2_rn(hx, hy)) * GAMMA_F;
    int A = *act_count;
    int count = 0;

    for (int c0 = 0; c0 < A && count < S; c0 += 256) {
        int i = c0 + tid;
        int pred = 0;
        float4 q = make_float4(0.f, 0.f, 0.f, 0.f);
        if (i < A) {
            q = actq[i];
            float d = sqrtf(sq2_rn(q.x - bx, q.y - by));
            pred = (d <= rad + q.z + SLACK_F) ? 1 : 0;   // superset of point test
        }
        unsigned long long bal = __ballot(pred != 0);
        if (lane == 0) wsum[wid] = __popcll(bal);
        __syncthreads();
        int cb = 0;
        for (int w = 0; w < wid; w++) cb += wsum[w];
        int tot = wsum[0] + wsum[1] + wsum[2] + wsum[3];
        if (pred) cq[cb + __popcll(bal & ltmask)] = q;
        __syncthreads();

        for (int g0 = 0; g0 < tot && count < S; g0 += 16) {
            int ci = g0 + (tid >> 4), k = tid & 15;
            int pred2 = 0;
            size_t n = 0;
            if (ci < tot) {
                float4 qq = cq[ci];
                int vn = __float_as_int(qq.w);
                int npv = vn >> 16, vid = vn & 0xFFFF;
                if (k < npv) {
                    n = (size_t)(vid * K + k);
                    float px = voxels[n * F + 0], py = voxels[n * F + 1];
                    pred2 = (sqrtf(sq2_rn(px - bx, py - by)) <= rad) ? 1 : 0;
                }
            }
            unsigned long long bal2 = __ballot(pred2 != 0);
            if (lane == 0) wsum[wid] = __popcll(bal2);
            __syncthreads();
            int wb = count;
            for (int w = 0; w < wid; w++) wb += wsum[w];
            int tot2 = wsum[0] + wsum[1] + wsum[2] + wsum[3];
            int pos = wb + __popcll(bal2 & ltmask);
            if (pred2 && pos < S) {
                const float* src = voxels + n * F;
                float* dst = out_kp + ((size_t)r * S + pos) * F;
                #pragma unroll
                for (int j = 0; j < 5; j++) dst[j] = src[j];
            }
            count += tot2;
            __syncthreads();
        }
    }

    int sc = count < S ? count : S;
    for (int s = tid; s < S; s += 256)
        out_mask[(size_t)r * S + s] = (s < sc) ? 1.0f : 0.0f;
    for (int j = tid; j < S * F; j += 256) {
        int s = j / F;
        if (s >= sc) out_kp[(size_t)r * S * F + j] = 0.0f;
    }
}

extern "C" void kernel_launch(void* const* d_in, const int* in_sizes, int n_in,
                              void* d_out, int out_size, void* d_ws, size_t ws_size,
                              hipStream_t stream) {
    const float* voxels   = (const float*)d_in[0];
    const float* boxes    = (const float*)d_in[1];
    const float* pc_start = (const float*)d_in[2];
    const int*   coords   = (const int*)d_in[3];
    const int*   num_pts  = (const int*)d_in[4];

    int V = in_sizes[4];                     // 20000
    int R = in_sizes[1] / 7;                 // 256
    int K = 16;
    int F = (in_sizes[0] / V) / K;           // 5
    int S = (out_size - V) / (R * (F + 1));  // 128
    int nb = (V + 63) / 64;                  // 313

    float* out_kp  = (float*)d_out;                 // [R,S,F]
    float* out_msk = out_kp + (size_t)R * S * F;    // [R,S]
    float* out_vox = out_msk + (size_t)R * S;       // [V]

    // workspace carve (256B aligned)
    char* w = (char*)d_ws;
    auto carve = [&](size_t bytes) {
        void* p = (void*)w;
        w += (bytes + 255) & ~(size_t)255;
        return p;
    };
    unsigned char* vstat   = (unsigned char*)carve((size_t)V);
    float*         vmaxoff = (float*)carve((size_t)V * 4);
    int*           bc      = (int*)carve((size_t)nb * 4);
    int*           actcnt  = (int*)carve(4);
    float4*        actq    = (float4*)carve((size_t)V * 16);

    k1_mask<<<nb, 64, 0, stream>>>(boxes, pc_start, coords, num_pts, voxels,
                                   V, R, K, F, vstat, vmaxoff, out_vox, bc);
    k2_compact<<<nb, 64, 0, stream>>>(vstat, vmaxoff, coords, pc_start,
                                      V, nb, bc, actq, actcnt);
    k3_roi<<<R, 256, 0, stream>>>(voxels, boxes, actq, actcnt,
                                  K, F, S, out_kp, out_msk);
}